// Round 2
// baseline (180.174 us; speedup 1.0000x reference)
//
#include <hip/hip_runtime.h>
#include <math.h>

#define NACC 32
// acc layout: 0 cnt, 1 sw, 2-4 swx, 5-7 swy, 8-16 swyx[o*3+i],
//             17-19 sx, 20-22 sy, 23-31 syx[o*3+i]

__device__ __forceinline__ void accum_point(float w, float x0, float x1, float x2,
                                            float y0, float y1, float y2, float* a) {
    a[0] += (w > 0.0f) ? 1.0f : 0.0f;
    a[1] += w;
    a[2] = fmaf(w, x0, a[2]); a[3] = fmaf(w, x1, a[3]); a[4] = fmaf(w, x2, a[4]);
    float wy0 = w * y0, wy1 = w * y1, wy2 = w * y2;
    a[5] += wy0; a[6] += wy1; a[7] += wy2;
    a[8]  = fmaf(wy0, x0, a[8]);  a[9]  = fmaf(wy0, x1, a[9]);  a[10] = fmaf(wy0, x2, a[10]);
    a[11] = fmaf(wy1, x0, a[11]); a[12] = fmaf(wy1, x1, a[12]); a[13] = fmaf(wy1, x2, a[13]);
    a[14] = fmaf(wy2, x0, a[14]); a[15] = fmaf(wy2, x1, a[15]); a[16] = fmaf(wy2, x2, a[16]);
    a[17] += x0; a[18] += x1; a[19] += x2;
    a[20] += y0; a[21] += y1; a[22] += y2;
    a[23] = fmaf(y0, x0, a[23]); a[24] = fmaf(y0, x1, a[24]); a[25] = fmaf(y0, x2, a[25]);
    a[26] = fmaf(y1, x0, a[26]); a[27] = fmaf(y1, x1, a[27]); a[28] = fmaf(y1, x2, a[28]);
    a[29] = fmaf(y2, x0, a[29]); a[30] = fmaf(y2, x1, a[30]); a[31] = fmaf(y2, x2, a[31]);
}

// consume one 4-point group given its 7 float4s
__device__ __forceinline__ void accum_group(float4 wv, float4 x0, float4 x1, float4 x2,
                                            float4 y0, float4 y1, float4 y2, float* a) {
    accum_point(wv.x, x0.x, x0.y, x0.z, y0.x, y0.y, y0.z, a);
    accum_point(wv.y, x0.w, x1.x, x1.y, y0.w, y1.x, y1.y, a);
    accum_point(wv.z, x1.z, x1.w, x2.x, y1.z, y1.w, y2.x, a);
    accum_point(wv.w, x2.y, x2.z, x2.w, y2.y, y2.z, y2.w, a);
}

__global__ __launch_bounds__(256) void kabsch_reduce(
    const float* __restrict__ c0, const float* __restrict__ c1,
    const float* __restrict__ w, int N, double* __restrict__ partials) {
    float a[NACC];
    #pragma unroll
    for (int i = 0; i < NACC; ++i) a[i] = 0.0f;

    int tid = blockIdx.x * blockDim.x + threadIdx.x;
    int nthreads = gridDim.x * blockDim.x;
    int ngroups = N >> 2;        // groups of 4 points (48B rows -> 16B-aligned float4s)
    int npairs = ngroups >> 1;   // pairs of groups: 8 points / 14 float4 loads per thread
    const float4* w4 = (const float4*)w;
    const float4* A4 = (const float4*)c0;
    const float4* B4 = (const float4*)c1;

    for (int p = tid; p < npairs; p += nthreads) {
        int g = p * 2;
        size_t base = (size_t)3 * (size_t)g;
        // issue all 14 loads up-front (224B in flight per thread)
        float4 wv0 = w4[g], wv1 = w4[g + 1];
        float4 ax0 = A4[base],     ax1 = A4[base + 1], ax2 = A4[base + 2];
        float4 ax3 = A4[base + 3], ax4 = A4[base + 4], ax5 = A4[base + 5];
        float4 by0 = B4[base],     by1 = B4[base + 1], by2 = B4[base + 2];
        float4 by3 = B4[base + 3], by4 = B4[base + 4], by5 = B4[base + 5];
        accum_group(wv0, ax0, ax1, ax2, by0, by1, by2, a);
        accum_group(wv1, ax3, ax4, ax5, by3, by4, by5, a);
    }
    if (tid == 0) {  // tails: odd trailing group + non-multiple-of-4 points
        if (npairs * 2 < ngroups) {
            int g = npairs * 2;
            size_t base = (size_t)3 * (size_t)g;
            accum_group(w4[g], A4[base], A4[base + 1], A4[base + 2],
                        B4[base], B4[base + 1], B4[base + 2], a);
        }
        for (int i = ngroups << 2; i < N; ++i)
            accum_point(w[i], c0[3*i], c0[3*i+1], c0[3*i+2],
                        c1[3*i], c1[3*i+1], c1[3*i+2], a);
    }

    // wave-level double reduction
    double d[NACC];
    #pragma unroll
    for (int i = 0; i < NACC; ++i) d[i] = (double)a[i];
    #pragma unroll
    for (int off = 32; off > 0; off >>= 1) {
        #pragma unroll
        for (int i = 0; i < NACC; ++i) d[i] += __shfl_down(d[i], off, 64);
    }

    __shared__ double sm[4][NACC];
    int wave = threadIdx.x >> 6, lane = threadIdx.x & 63;
    if (lane == 0) {
        #pragma unroll
        for (int i = 0; i < NACC; ++i) sm[wave][i] = d[i];
    }
    __syncthreads();
    if (threadIdx.x == 0) {
        #pragma unroll
        for (int i = 0; i < NACC; ++i)
            partials[(size_t)blockIdx.x * NACC + i] = sm[0][i] + sm[1][i] + sm[2][i] + sm[3][i];
    }
}

__device__ __forceinline__ double det3(const double m[3][3]) {
    return m[0][0] * (m[1][1] * m[2][2] - m[1][2] * m[2][1])
         - m[0][1] * (m[1][0] * m[2][2] - m[1][2] * m[2][0])
         + m[0][2] * (m[1][0] * m[2][1] - m[1][1] * m[2][0]);
}

__global__ __launch_bounds__(256) void kabsch_finalize(
    const double* __restrict__ partials, int nparts, int N, float* __restrict__ out) {
    double d[NACC];
    #pragma unroll
    for (int i = 0; i < NACC; ++i) d[i] = 0.0;
    for (int r = threadIdx.x; r < nparts; r += 256) {
        #pragma unroll
        for (int i = 0; i < NACC; ++i) d[i] += partials[(size_t)r * NACC + i];
    }
    #pragma unroll
    for (int off = 32; off > 0; off >>= 1) {
        #pragma unroll
        for (int i = 0; i < NACC; ++i) d[i] += __shfl_down(d[i], off, 64);
    }
    __shared__ double sm[4][NACC];
    int wave = threadIdx.x >> 6, lane = threadIdx.x & 63;
    if (lane == 0) {
        #pragma unroll
        for (int i = 0; i < NACC; ++i) sm[wave][i] = d[i];
    }
    __syncthreads();
    if (threadIdx.x != 0) return;
    #pragma unroll
    for (int i = 0; i < NACC; ++i) d[i] = sm[0][i] + sm[1][i] + sm[2][i] + sm[3][i];

    const double EPSF = (double)1.1920929e-7f;  // float32 eps
    double cnt = d[0];
    double W = d[1];
    double swx[3] = { d[2], d[3], d[4] };
    double swy[3] = { d[5], d[6], d[7] };
    double swyx[9];
    for (int i = 0; i < 9; ++i) swyx[i] = d[8 + i];
    bool nep = cnt < 3.0;
    if (nep) {  // weights += EPS everywhere, applied analytically
        W += EPSF * (double)N;
        for (int i = 0; i < 3; ++i) { swx[i] += EPSF * d[17 + i]; swy[i] += EPSF * d[20 + i]; }
        for (int i = 0; i < 9; ++i) swyx[i] += EPSF * d[23 + i];
    }

    double mx[3], my[3];
    for (int i = 0; i < 3; ++i) { mx[i] = swx[i] / W; my[i] = swy[i] / W; }
    double S[3][3];
    for (int o = 0; o < 3; ++o)
        for (int i = 0; i < 3; ++i)
            S[o][i] = swyx[o * 3 + i] / W - my[o] * mx[i];

    // Jacobi eigendecomposition of B = S^T S  ->  V, lam
    double Bm[3][3], V[3][3];
    for (int i = 0; i < 3; ++i)
        for (int j = 0; j < 3; ++j) {
            double acc = 0.0;
            for (int k = 0; k < 3; ++k) acc += S[k][i] * S[k][j];
            Bm[i][j] = acc;
            V[i][j] = (i == j) ? 1.0 : 0.0;
        }
    for (int sweep = 0; sweep < 30; ++sweep) {
        double off2 = Bm[0][1]*Bm[0][1] + Bm[0][2]*Bm[0][2] + Bm[1][2]*Bm[1][2];
        double diag2 = Bm[0][0]*Bm[0][0] + Bm[1][1]*Bm[1][1] + Bm[2][2]*Bm[2][2];
        if (off2 <= diag2 * 1e-32 + 1e-300) break;
        for (int pair = 0; pair < 3; ++pair) {
            int p = (pair == 2) ? 1 : 0;
            int q = (pair == 0) ? 1 : 2;
            double apq = Bm[p][q];
            if (fabs(apq) < 1e-300) continue;
            double theta = (Bm[q][q] - Bm[p][p]) / (2.0 * apq);
            double t = ((theta >= 0.0) ? 1.0 : -1.0) / (fabs(theta) + sqrt(1.0 + theta * theta));
            double c = 1.0 / sqrt(1.0 + t * t);
            double sn = t * c;
            for (int k = 0; k < 3; ++k) {  // B = B*G
                double bkp = Bm[k][p], bkq = Bm[k][q];
                Bm[k][p] = c * bkp - sn * bkq;
                Bm[k][q] = sn * bkp + c * bkq;
            }
            for (int k = 0; k < 3; ++k) {  // B = G^T*B
                double bpk = Bm[p][k], bqk = Bm[q][k];
                Bm[p][k] = c * bpk - sn * bqk;
                Bm[q][k] = sn * bpk + c * bqk;
            }
            for (int k = 0; k < 3; ++k) {  // V = V*G
                double vkp = V[k][p], vkq = V[k][q];
                V[k][p] = c * vkp - sn * vkq;
                V[k][q] = sn * vkp + c * vkq;
            }
        }
    }
    double lam[3] = { Bm[0][0], Bm[1][1], Bm[2][2] };
    // sort eigenvalues descending, permute V columns
    for (int i = 0; i < 2; ++i)
        for (int j = i + 1; j < 3; ++j)
            if (lam[j] > lam[i]) {
                double tl = lam[i]; lam[i] = lam[j]; lam[j] = tl;
                for (int k = 0; k < 3; ++k) { double tv = V[k][i]; V[k][i] = V[k][j]; V[k][j] = tv; }
            }
    double sig[3];
    for (int i = 0; i < 3; ++i) sig[i] = sqrt(fmax(lam[i], 0.0));

    // U columns = S*v_i / ||S*v_i||  (fallbacks for degenerate directions)
    double U[3][3];
    for (int i = 0; i < 3; ++i) {
        double u0 = S[0][0]*V[0][i] + S[0][1]*V[1][i] + S[0][2]*V[2][i];
        double u1 = S[1][0]*V[0][i] + S[1][1]*V[1][i] + S[1][2]*V[2][i];
        double u2 = S[2][0]*V[0][i] + S[2][1]*V[1][i] + S[2][2]*V[2][i];
        double nrm = sqrt(u0*u0 + u1*u1 + u2*u2);
        if (nrm > 1e-150) {
            U[0][i] = u0 / nrm; U[1][i] = u1 / nrm; U[2][i] = u2 / nrm;
        } else if (i == 0) {
            U[0][0] = 1.0; U[1][0] = 0.0; U[2][0] = 0.0;
        } else if (i == 1) {
            double e0 = (fabs(U[0][0]) < 0.9) ? 1.0 : 0.0;
            double e1 = 1.0 - e0;
            double dp = e0 * U[0][0] + e1 * U[1][0];
            double v0 = e0 - dp * U[0][0], v1 = e1 - dp * U[1][0], v2 = -dp * U[2][0];
            double n2 = sqrt(v0*v0 + v1*v1 + v2*v2);
            U[0][1] = v0 / n2; U[1][1] = v1 / n2; U[2][1] = v2 / n2;
        } else {
            U[0][2] = U[1][0]*U[2][1] - U[2][0]*U[1][1];
            U[1][2] = U[2][0]*U[0][1] - U[0][0]*U[2][1];
            U[2][2] = U[0][0]*U[1][1] - U[1][0]*U[0][1];
        }
    }

    double tol = sig[0] * 3.0 * EPSF;
    int rank = (sig[0] > tol) + (sig[1] > tol) + (sig[2] > tol);
    double detS = det3(S);
    double det_mul = det3(U) * det3(V);
    double sign_full = (detS < 0.0) ? -1.0 : 1.0;
    double sign_def = (fabs(det_mul + 1.0) <= 1.00001e-5) ? -1.0 : 1.0;
    double s = (rank > 2) ? sign_full : sign_def;

    double R[3][3];
    for (int o = 0; o < 3; ++o)
        for (int i = 0; i < 3; ++i)
            R[o][i] = U[o][0]*V[i][0] + U[o][1]*V[i][1] + s * U[o][2]*V[i][2];
    double tv[3];
    for (int o = 0; o < 3; ++o)
        tv[o] = my[o] - (R[o][0]*mx[0] + R[o][1]*mx[1] + R[o][2]*mx[2]);

    // T row-major 4x4, then not_enough_points flag
    for (int o = 0; o < 3; ++o) {
        out[o * 4 + 0] = (float)R[o][0];
        out[o * 4 + 1] = (float)R[o][1];
        out[o * 4 + 2] = (float)R[o][2];
        out[o * 4 + 3] = (float)tv[o];
    }
    out[12] = 0.0f; out[13] = 0.0f; out[14] = 0.0f; out[15] = 1.0f;
    out[16] = nep ? 1.0f : 0.0f;
}

extern "C" void kernel_launch(void* const* d_in, const int* in_sizes, int n_in,
                              void* d_out, int out_size, void* d_ws, size_t ws_size,
                              hipStream_t stream) {
    const float* c0 = (const float*)d_in[0];
    const float* c1 = (const float*)d_in[1];
    const float* w  = (const float*)d_in[2];
    float* out = (float*)d_out;
    int N = in_sizes[2];  // B=1: weights has N elements

    int blocks = 2048;   // 8 blocks/CU on 256 CUs; VGPR=68 -> ~7 waves/SIMD resident
    size_t need = (size_t)blocks * NACC * sizeof(double);
    if (need > ws_size) {
        blocks = (int)(ws_size / (NACC * sizeof(double)));
        if (blocks < 1) blocks = 1;
    }
    double* partials = (double*)d_ws;

    kabsch_reduce<<<blocks, 256, 0, stream>>>(c0, c1, w, N, partials);
    kabsch_finalize<<<1, 256, 0, stream>>>(partials, blocks, N, out);
}

// Round 3
// 153.601 us; speedup vs baseline: 1.1730x; 1.1730x over previous
//
#include <hip/hip_runtime.h>
#include <math.h>

#define NACC 32
#define TILE 1024   // points per tile: A/B = 12KB raw -> 16KB padded in LDS, w = 4KB
// acc layout: 0 cnt, 1 sw, 2-4 swx, 5-7 swy, 8-16 swyx[o*3+i],
//             17-19 sx, 20-22 sy, 23-31 syx[o*3+i]

__device__ __forceinline__ void accum_point(float w, float x0, float x1, float x2,
                                            float y0, float y1, float y2, float* a) {
    a[0] += (w > 0.0f) ? 1.0f : 0.0f;
    a[1] += w;
    a[2] = fmaf(w, x0, a[2]); a[3] = fmaf(w, x1, a[3]); a[4] = fmaf(w, x2, a[4]);
    float wy0 = w * y0, wy1 = w * y1, wy2 = w * y2;
    a[5] += wy0; a[6] += wy1; a[7] += wy2;
    a[8]  = fmaf(wy0, x0, a[8]);  a[9]  = fmaf(wy0, x1, a[9]);  a[10] = fmaf(wy0, x2, a[10]);
    a[11] = fmaf(wy1, x0, a[11]); a[12] = fmaf(wy1, x1, a[12]); a[13] = fmaf(wy1, x2, a[13]);
    a[14] = fmaf(wy2, x0, a[14]); a[15] = fmaf(wy2, x1, a[15]); a[16] = fmaf(wy2, x2, a[16]);
    a[17] += x0; a[18] += x1; a[19] += x2;
    a[20] += y0; a[21] += y1; a[22] += y2;
    a[23] = fmaf(y0, x0, a[23]); a[24] = fmaf(y0, x1, a[24]); a[25] = fmaf(y0, x2, a[25]);
    a[26] = fmaf(y1, x0, a[26]); a[27] = fmaf(y1, x1, a[27]); a[28] = fmaf(y1, x2, a[28]);
    a[29] = fmaf(y2, x0, a[29]); a[30] = fmaf(y2, x1, a[30]); a[31] = fmaf(y2, x2, a[31]);
}

__global__ __launch_bounds__(256) void kabsch_reduce(
    const float* __restrict__ c0, const float* __restrict__ c1,
    const float* __restrict__ w, int N, float* __restrict__ partials, int nblocks) {
    __shared__ float4 sA[TILE];          // point-padded: {x0,x1,x2,junk}
    __shared__ float4 sB[TILE];
    __shared__ float  sw[TILE];
    __shared__ float  wred[4][NACC];

    float a[NACC];
    #pragma unroll
    for (int i = 0; i < NACC; ++i) a[i] = 0.0f;

    const int t = threadIdx.x;
    const int lane = t & 63, wave = t >> 6;
    const float4* A4 = (const float4*)c0;
    const float4* B4 = (const float4*)c1;
    const float4* W4 = (const float4*)w;
    float* fA = (float*)sA;
    float* fB = (float*)sB;

    int nfull = N >> 10;  // full 1024-point tiles

    for (int tile = blockIdx.x; tile < nfull; tile += gridDim.x) {
        int baseAB = tile * 768;   // float4 index into A/B (1024 pts * 3 / 4)
        // ---- stage: lane-contiguous float4 loads (1KB per wave-instruction),
        //      scatter-pad into LDS (bank spread ~2-way = free) ----
        #pragma unroll
        for (int k = 0; k < 3; ++k) {
            int idx = (k << 8) + t;
            float4 va = A4[baseAB + idx];
            float4 vb = B4[baseAB + idx];
            unsigned flat0 = (unsigned)idx << 2;
            float aa[4] = { va.x, va.y, va.z, va.w };
            float bb[4] = { vb.x, vb.y, vb.z, vb.w };
            #pragma unroll
            for (int j = 0; j < 4; ++j) {
                unsigned f = flat0 + j;
                unsigned p = (f * 21846u) >> 16;   // f/3, exact for f < 32768
                unsigned cc = f - p * 3u;
                fA[(p << 2) | cc] = aa[j];
                fB[(p << 2) | cc] = bb[j];
            }
        }
        ((float4*)sw)[t] = W4[(tile << 8) + t];
        __syncthreads();
        // ---- compute: conflict-free ds_read_b128 (16B lane stride) ----
        #pragma unroll
        for (int k = 0; k < 4; ++k) {
            int p = t + (k << 8);
            float4 xa = sA[p];
            float4 xb = sB[p];
            float wt = sw[p];
            accum_point(wt, xa.x, xa.y, xa.z, xb.x, xb.y, xb.z, a);
        }
        __syncthreads();
    }
    // tail points (N % 1024) — never taken for N = 4M, correctness-general
    if (blockIdx.x == 0 && t == 0) {
        for (int i = nfull << 10; i < N; ++i)
            accum_point(w[i], c0[3*i], c0[3*i+1], c0[3*i+2],
                        c1[3*i], c1[3*i+1], c1[3*i+2], a);
    }

    // ---- multi-value butterfly wave reduction: 32 accs in 32 shuffles.
    // After stage dist=2^k, slot i holds acc (i + half*bit_k(lane)) summed
    // over lane-pairs; final mapping lane -> acc = bitrev5(lane&31). ----
    {
        int hi;
        hi = lane & 1;
        #pragma unroll
        for (int i = 0; i < 16; ++i) {
            float send = hi ? a[i] : a[i + 16];
            float recv = __shfl_xor(send, 1, 64);
            a[i] = (hi ? a[i + 16] : a[i]) + recv;
        }
        hi = lane & 2;
        #pragma unroll
        for (int i = 0; i < 8; ++i) {
            float send = hi ? a[i] : a[i + 8];
            float recv = __shfl_xor(send, 2, 64);
            a[i] = (hi ? a[i + 8] : a[i]) + recv;
        }
        hi = lane & 4;
        #pragma unroll
        for (int i = 0; i < 4; ++i) {
            float send = hi ? a[i] : a[i + 4];
            float recv = __shfl_xor(send, 4, 64);
            a[i] = (hi ? a[i + 4] : a[i]) + recv;
        }
        hi = lane & 8;
        #pragma unroll
        for (int i = 0; i < 2; ++i) {
            float send = hi ? a[i] : a[i + 2];
            float recv = __shfl_xor(send, 8, 64);
            a[i] = (hi ? a[i + 2] : a[i]) + recv;
        }
        hi = lane & 16;
        {
            float send = hi ? a[0] : a[1];
            float recv = __shfl_xor(send, 16, 64);
            a[0] = (hi ? a[1] : a[0]) + recv;
        }
        a[0] += __shfl_xor(a[0], 32, 64);
    }
    if (lane < 32) {
        int acc = ((lane & 1) << 4) | ((lane & 2) << 2) | (lane & 4)
                | ((lane & 8) >> 2) | ((lane & 16) >> 4);  // bitrev5
        wred[wave][acc] = a[0];
    }
    __syncthreads();
    if (t < NACC)
        partials[t * nblocks + blockIdx.x] =
            wred[0][t] + wred[1][t] + wred[2][t] + wred[3][t];
}

__device__ __forceinline__ double det3(const double m[3][3]) {
    return m[0][0] * (m[1][1] * m[2][2] - m[1][2] * m[2][1])
         - m[0][1] * (m[1][0] * m[2][2] - m[1][2] * m[2][0])
         + m[0][2] * (m[1][0] * m[2][1] - m[1][1] * m[2][0]);
}

__global__ __launch_bounds__(256) void kabsch_finalize(
    const float* __restrict__ partials, int nblocks, int N, float* __restrict__ out) {
    double d[NACC];
    #pragma unroll
    for (int i = 0; i < NACC; ++i) d[i] = 0.0;
    for (int m = threadIdx.x; m < nblocks; m += 256) {
        #pragma unroll
        for (int i = 0; i < NACC; ++i)
            d[i] += (double)partials[i * nblocks + m];   // lane-contiguous per i
    }
    #pragma unroll
    for (int off = 32; off > 0; off >>= 1) {
        #pragma unroll
        for (int i = 0; i < NACC; ++i) d[i] += __shfl_down(d[i], off, 64);
    }
    __shared__ double sm[4][NACC];
    int wave = threadIdx.x >> 6, lane = threadIdx.x & 63;
    if (lane == 0) {
        #pragma unroll
        for (int i = 0; i < NACC; ++i) sm[wave][i] = d[i];
    }
    __syncthreads();
    if (threadIdx.x != 0) return;
    #pragma unroll
    for (int i = 0; i < NACC; ++i) d[i] = sm[0][i] + sm[1][i] + sm[2][i] + sm[3][i];

    const double EPSF = (double)1.1920929e-7f;  // float32 eps
    double cnt = d[0];
    double W = d[1];
    double swx[3] = { d[2], d[3], d[4] };
    double swy[3] = { d[5], d[6], d[7] };
    double swyx[9];
    for (int i = 0; i < 9; ++i) swyx[i] = d[8 + i];
    bool nep = cnt < 3.0;
    if (nep) {  // weights += EPS everywhere, applied analytically
        W += EPSF * (double)N;
        for (int i = 0; i < 3; ++i) { swx[i] += EPSF * d[17 + i]; swy[i] += EPSF * d[20 + i]; }
        for (int i = 0; i < 9; ++i) swyx[i] += EPSF * d[23 + i];
    }

    double mx[3], my[3];
    for (int i = 0; i < 3; ++i) { mx[i] = swx[i] / W; my[i] = swy[i] / W; }
    double S[3][3];
    for (int o = 0; o < 3; ++o)
        for (int i = 0; i < 3; ++i)
            S[o][i] = swyx[o * 3 + i] / W - my[o] * mx[i];

    // Jacobi eigendecomposition of B = S^T S  ->  V, lam
    double Bm[3][3], V[3][3];
    for (int i = 0; i < 3; ++i)
        for (int j = 0; j < 3; ++j) {
            double acc = 0.0;
            for (int k = 0; k < 3; ++k) acc += S[k][i] * S[k][j];
            Bm[i][j] = acc;
            V[i][j] = (i == j) ? 1.0 : 0.0;
        }
    for (int sweep = 0; sweep < 30; ++sweep) {
        double off2 = Bm[0][1]*Bm[0][1] + Bm[0][2]*Bm[0][2] + Bm[1][2]*Bm[1][2];
        double diag2 = Bm[0][0]*Bm[0][0] + Bm[1][1]*Bm[1][1] + Bm[2][2]*Bm[2][2];
        if (off2 <= diag2 * 1e-32 + 1e-300) break;
        for (int pair = 0; pair < 3; ++pair) {
            int p = (pair == 2) ? 1 : 0;
            int q = (pair == 0) ? 1 : 2;
            double apq = Bm[p][q];
            if (fabs(apq) < 1e-300) continue;
            double theta = (Bm[q][q] - Bm[p][p]) / (2.0 * apq);
            double tt = ((theta >= 0.0) ? 1.0 : -1.0) / (fabs(theta) + sqrt(1.0 + theta * theta));
            double c = 1.0 / sqrt(1.0 + tt * tt);
            double sn = tt * c;
            for (int k = 0; k < 3; ++k) {
                double bkp = Bm[k][p], bkq = Bm[k][q];
                Bm[k][p] = c * bkp - sn * bkq;
                Bm[k][q] = sn * bkp + c * bkq;
            }
            for (int k = 0; k < 3; ++k) {
                double bpk = Bm[p][k], bqk = Bm[q][k];
                Bm[p][k] = c * bpk - sn * bqk;
                Bm[q][k] = sn * bpk + c * bqk;
            }
            for (int k = 0; k < 3; ++k) {
                double vkp = V[k][p], vkq = V[k][q];
                V[k][p] = c * vkp - sn * vkq;
                V[k][q] = sn * vkp + c * vkq;
            }
        }
    }
    double lam[3] = { Bm[0][0], Bm[1][1], Bm[2][2] };
    for (int i = 0; i < 2; ++i)
        for (int j = i + 1; j < 3; ++j)
            if (lam[j] > lam[i]) {
                double tl = lam[i]; lam[i] = lam[j]; lam[j] = tl;
                for (int k = 0; k < 3; ++k) { double tv = V[k][i]; V[k][i] = V[k][j]; V[k][j] = tv; }
            }
    double sig[3];
    for (int i = 0; i < 3; ++i) sig[i] = sqrt(fmax(lam[i], 0.0));

    double U[3][3];
    for (int i = 0; i < 3; ++i) {
        double u0 = S[0][0]*V[0][i] + S[0][1]*V[1][i] + S[0][2]*V[2][i];
        double u1 = S[1][0]*V[0][i] + S[1][1]*V[1][i] + S[1][2]*V[2][i];
        double u2 = S[2][0]*V[0][i] + S[2][1]*V[1][i] + S[2][2]*V[2][i];
        double nrm = sqrt(u0*u0 + u1*u1 + u2*u2);
        if (nrm > 1e-150) {
            U[0][i] = u0 / nrm; U[1][i] = u1 / nrm; U[2][i] = u2 / nrm;
        } else if (i == 0) {
            U[0][0] = 1.0; U[1][0] = 0.0; U[2][0] = 0.0;
        } else if (i == 1) {
            double e0 = (fabs(U[0][0]) < 0.9) ? 1.0 : 0.0;
            double e1 = 1.0 - e0;
            double dp = e0 * U[0][0] + e1 * U[1][0];
            double v0 = e0 - dp * U[0][0], v1 = e1 - dp * U[1][0], v2 = -dp * U[2][0];
            double n2 = sqrt(v0*v0 + v1*v1 + v2*v2);
            U[0][1] = v0 / n2; U[1][1] = v1 / n2; U[2][1] = v2 / n2;
        } else {
            U[0][2] = U[1][0]*U[2][1] - U[2][0]*U[1][1];
            U[1][2] = U[2][0]*U[0][1] - U[0][0]*U[2][1];
            U[2][2] = U[0][0]*U[1][1] - U[1][0]*U[0][1];
        }
    }

    double tol = sig[0] * 3.0 * EPSF;
    int rank = (sig[0] > tol) + (sig[1] > tol) + (sig[2] > tol);
    double detS = det3(S);
    double det_mul = det3(U) * det3(V);
    double sign_full = (detS < 0.0) ? -1.0 : 1.0;
    double sign_def = (fabs(det_mul + 1.0) <= 1.00001e-5) ? -1.0 : 1.0;
    double s = (rank > 2) ? sign_full : sign_def;

    double R[3][3];
    for (int o = 0; o < 3; ++o)
        for (int i = 0; i < 3; ++i)
            R[o][i] = U[o][0]*V[i][0] + U[o][1]*V[i][1] + s * U[o][2]*V[i][2];
    double tv[3];
    for (int o = 0; o < 3; ++o)
        tv[o] = my[o] - (R[o][0]*mx[0] + R[o][1]*mx[1] + R[o][2]*mx[2]);

    for (int o = 0; o < 3; ++o) {
        out[o * 4 + 0] = (float)R[o][0];
        out[o * 4 + 1] = (float)R[o][1];
        out[o * 4 + 2] = (float)R[o][2];
        out[o * 4 + 3] = (float)tv[o];
    }
    out[12] = 0.0f; out[13] = 0.0f; out[14] = 0.0f; out[15] = 1.0f;
    out[16] = nep ? 1.0f : 0.0f;
}

extern "C" void kernel_launch(void* const* d_in, const int* in_sizes, int n_in,
                              void* d_out, int out_size, void* d_ws, size_t ws_size,
                              hipStream_t stream) {
    const float* c0 = (const float*)d_in[0];
    const float* c1 = (const float*)d_in[1];
    const float* w  = (const float*)d_in[2];
    float* out = (float*)d_out;
    int N = in_sizes[2];  // B=1: weights has N elements

    int blocks = 1024;   // 4 blocks/CU (36.5KB LDS each), 4 tiles/block
    size_t need = (size_t)blocks * NACC * sizeof(float);
    if (need > ws_size) {
        blocks = (int)(ws_size / (NACC * sizeof(float)));
        if (blocks < 1) blocks = 1;
    }
    float* partials = (float*)d_ws;   // layout: [acc][block] (transposed)

    kabsch_reduce<<<blocks, 256, 0, stream>>>(c0, c1, w, N, partials, blocks);
    kabsch_finalize<<<1, 256, 0, stream>>>(partials, blocks, N, out);
}